// Round 10
// baseline (90.935 us; speedup 1.0000x reference)
//
#include <hip/hip_runtime.h>

#define NXS    65536
#define HID    32
#define BTL    512           // 8 waves per block
#define NB     256           // blocks (= CUs); 2048 waves = 2/SIMD
#define OWNB   256           // cells owned (output) per block
#define MARG   100           // halo per side per launch (h <= MARG)
#define SSPAN  (OWNB + 2 * MARG)     // 456 cells spanned per block
#define CC     3             // cells per lane; wave slab = 192 cells
#define EPOCH  62            // steps between refills
#define LUT_N  4096
#define LUT_INV  512.0f      // entries per unit c, range [-4,4)
#define LUT_BIAS 2048.0f

__device__ __forceinline__ float fexp2(float x) { return __builtin_amdgcn_exp2f(x); }
__device__ __forceinline__ float frcp(float x)  { return __builtin_amdgcn_rcpf(x); }
__device__ __forceinline__ float flog2(float x) { return __builtin_amdgcn_logf(x); }

__device__ __forceinline__ float fast_tanh(float x) {
    x = fminf(fmaxf(x, -15.0f), 15.0f);
    float e = fexp2(x * 2.8853900817779268f);   // e^{2x}
    return (e - 1.0f) * frcp(e + 1.0f);
}
__device__ __forceinline__ float fast_sigmoid(float x) {
    float e = fexp2(x * -1.4426950408889634f);
    return frcp(1.0f + e);
}

struct FinnPtrs {
    const float* tvec;
    const float* Dp;  const float* stencil; const float* BCp; const float* fp;
    const float* kdp; const float* betap;   const float* alphap; const float* rhosp;
    const float* nep; const float* vep;     const float* dxp;
};

// ---- Kernel 1: tabulate ret(c) AND clip(c)^beta on [-4,4], LUT_N+1 entries ----
__global__ __launch_bounds__(256) void finn_lut(
    const float* __restrict__ W0, const float* __restrict__ b0,
    const float* __restrict__ W1, const float* __restrict__ b1,
    const float* __restrict__ W2, const float* __restrict__ b2,
    const float* __restrict__ W3, const float* __restrict__ b3,
    const float* __restrict__ ret_fac, const float* __restrict__ betap,
    float* __restrict__ lut_ret, float* __restrict__ lut_pw)
{
    const int i = blockIdx.x * 256 + threadIdx.x;
    if (i > LUT_N) return;                       // LUT_N+1 entries
    const float c = -4.0f + (float)i * (1.0f / LUT_INV);

    float h[HID], a[HID];
    #pragma unroll
    for (int j = 0; j < HID; ++j)
        h[j] = fast_tanh(fmaf(c, W0[j], b0[j]));

    #pragma unroll
    for (int j = 0; j < HID; ++j) a[j] = b1[j];
    #pragma unroll
    for (int k = 0; k < HID; ++k) {
        const float hk = h[k];
        #pragma unroll
        for (int j = 0; j < HID; ++j) a[j] = fmaf(hk, W1[k * HID + j], a[j]);
    }
    #pragma unroll
    for (int j = 0; j < HID; ++j) h[j] = fast_tanh(a[j]);

    #pragma unroll
    for (int j = 0; j < HID; ++j) a[j] = b2[j];
    #pragma unroll
    for (int k = 0; k < HID; ++k) {
        const float hk = h[k];
        #pragma unroll
        for (int j = 0; j < HID; ++j) a[j] = fmaf(hk, W2[k * HID + j], a[j]);
    }
    #pragma unroll
    for (int j = 0; j < HID; ++j) h[j] = fast_tanh(a[j]);

    float pre = b3[0];
    #pragma unroll
    for (int k = 0; k < HID; ++k) pre = fmaf(h[k], W3[k], pre);

    lut_ret[i] = fast_sigmoid(pre) * ret_fac[0];
    lut_pw[i]  = fexp2(betap[0] * flog2(fmaxf(c, 1e-9f)));   // clip(c)^beta
}

// ---- Kernel 2: epoch-refill sweep, fused (ret,pw) b128 LUT, wide VGPR budget ----
__global__ __launch_bounds__(BTL, 2) void finn_sweep(
    const float* __restrict__ uin, float* __restrict__ out,
    const float* __restrict__ lr_g, const float* __restrict__ lp_g,
    FinnPtrs P, int T)
{
    __shared__ float4 slut[LUT_N];    // (ret_sl, ret_ic, pw_sl, pw_ic), 64 KB
    __shared__ float2 xbuf[SSPAN];    // refill exchange

    const int tid  = threadIdx.x;
    const int w    = tid >> 6;
    const int lane = tid & 63;

    // build slope/intercept LUT: f(tt) = fmaf(tt, sl, ic) with absolute tt
    for (int i = tid; i < LUT_N; i += BTL) {
        const float r0 = lr_g[i], r1 = lr_g[i + 1];
        const float p0 = lp_g[i], p1 = lp_g[i + 1];
        const float rs = r1 - r0, ps = p1 - p0;
        slut[i] = make_float4(rs, fmaf(-(float)i, rs, r0),
                              ps, fmaf(-(float)i, ps, p0));
    }

    // wave-uniform scalars
    const float dt   = P.tvec[1] - P.tvec[0];
    const float s0   = P.stencil[0];
    const float s1   = P.stencil[1];
    const float dx   = P.dxp[0];
    const float A    = P.Dp[0] / (dx * dx);
    const float B    = P.vep[0] / dx;
    const float BC   = P.BCp[0];
    const float alp  = P.alphap[0];
    const float akd  = (1.0f - P.fp[0]) * P.kdp[0];
    const float rsne = P.rhosp[0] / P.nep[0];

    const float G    = dt * rsne * alp;
    const float GAKD = G * akd;
    const float S1c  = 1.0f - dt * alp;
    const float S2c  = dt * alp * akd;
    const float K1u  = dt * (2.0f * A * s0 - B);
    const float K2u  = dt * (A * s1 + B);
    const float K3u  = dt * A * s1;

    const int b = blockIdx.x;
    int blockBase = b * OWNB - MARG;
    if (blockBase < 0) blockBase = 0;
    if (blockBase > NXS - SSPAN) blockBase = NXS - SSPAN;
    const bool leftA  = (blockBase == 0);
    const bool rightA = (blockBase == NXS - SSPAN);
    const int ownRelL = b * OWNB - blockBase;
    const int ownRelR = ownRelL + OWNB;

    // epoch-0 slab base (valid window = [0, SSPAN))
    int a = ((SSPAN - 192) * w) / 7;

    float c[CC], sk[CC];
    {
        const float2* __restrict__ in2 = reinterpret_cast<const float2*>(uin);
        #pragma unroll
        for (int j = 0; j < CC; ++j) {
            const float2 u = in2[blockBase + a + lane * CC + j];
            c[j] = u.x; sk[j] = u.y;
        }
    }
    __syncthreads();   // slut ready

    char* __restrict__ outc = reinterpret_cast<char*>(out);
    int done = 0;
    while (done < T) {
        int nst = T - done; if (nst > EPOCH) nst = EPOCH;

        // ---- per-epoch setup ----
        const int vL = leftA ? 0 : done;
        const int vR = rightA ? SSPAN : SSPAN - done;
        const int pd = vR - vL - 192;
        const int aPrev = vL + (pd * (w - 1)) / 7;
        const int aNext = vL + (pd * (w + 1)) / 7;
        int bLo = (w == 0) ? 0     : ((aPrev + 192 + a) >> 1);
        int bHi = (w == 7) ? SSPAN : ((a + 192 + aNext) >> 1);
        if (bLo < ownRelL) bLo = ownRelL;
        if (bHi > ownRelR) bHi = ownRelR;

        float K0[CC], K1[CC], K2[CC], K3[CC];
        bool st[CC];
        #pragma unroll
        for (int j = 0; j < CC; ++j) {
            const int si = a + lane * CC + j;
            const int g  = blockBase + si;
            st[j] = (si >= bLo) && (si < bHi);
            K0[j] = 0.0f; K1[j] = K1u; K2[j] = K2u; K3[j] = K3u;
            if (g == 0)       { K0[j] = dt * BC * (2.0f * A * s1 + B);
                                K1[j] = dt * (3.0f * A * s0 - B);
                                K2[j] = 0.0f; }
            if (g == NXS - 1) { K1[j] = dt * (2.0f * A * s0 - B + A * s1);
                                K3[j] = 0.0f; }
        }
        unsigned off = (unsigned)(done * NXS + blockBase + a + lane * CC) * 8u;

        // comms prologue for first step of epoch
        float clS = __shfl_up(c[CC - 1], 1);
        float crS = __shfl_down(c[0], 1);
        float tt[CC]; float4 L[CC];
        #pragma unroll
        for (int j = 0; j < CC; ++j) {
            const float t2 = __builtin_amdgcn_fmed3f(
                fmaf(c[j], LUT_INV, LUT_BIAS), 0.0f, 4095.9f);
            tt[j] = t2; L[j] = slut[(int)t2];
        }

        // ---- inner loop: no barriers ----
        for (int s = 0; s < nst; ++s) {
            float nc[CC], nsk[CC];
            #pragma unroll
            for (int j = 0; j < CC; ++j) {
                const float cj  = c[j];
                const float ret = fmaf(tt[j], L[j].x, L[j].y);
                const float pw  = fmaf(tt[j], L[j].z, L[j].w);
                const float cl  = (j == 0)      ? clS : c[j - 1];
                const float cr  = (j == CC - 1) ? crS : c[j + 1];
                float t_ = fmaf(K1[j], cj, K0[j]);
                t_ = fmaf(K2[j], cl, t_);
                t_ = fmaf(K3[j], cr, t_);
                float v = fmaf(ret, t_, cj);
                v = fmaf(-GAKD, pw, v);
                nc[j]  = fmaf(G, sk[j], v);
                nsk[j] = fmaf(S1c, sk[j], S2c * pw);
            }
            #pragma unroll
            for (int j = 0; j < CC; ++j) { c[j] = nc[j]; sk[j] = nsk[j]; }

            // comms for next step (latency hidden under this step's tail)
            clS = __shfl_up(c[CC - 1], 1);
            crS = __shfl_down(c[0], 1);
            #pragma unroll
            for (int j = 0; j < CC; ++j) {
                const float t2 = __builtin_amdgcn_fmed3f(
                    fmaf(c[j], LUT_INV, LUT_BIAS), 0.0f, 4095.9f);
                tt[j] = t2; L[j] = slut[(int)t2];
            }

            // trajectory stores (disjoint windows, fire-and-forget)
            #pragma unroll
            for (int j = 0; j < CC; ++j)
                if (st[j])
                    *reinterpret_cast<float2*>(outc + (off + 8u * j)) =
                        make_float2(c[j], sk[j]);
            off += (unsigned)(NXS * 8);
        }

        done += nst;
        if (done >= T) break;

        // ---- refill: write valid cores, re-tile slabs ----
        __syncthreads();
        {
            const int wLo = (w == 0 && leftA)  ? 0   : EPOCH;
            const int wHi = (w == 7 && rightA) ? 192 : 192 - EPOCH;
            #pragma unroll
            for (int j = 0; j < CC; ++j) {
                const int si = lane * CC + j;
                if (si >= wLo && si < wHi)
                    xbuf[a + si] = make_float2(c[j], sk[j]);
            }
        }
        __syncthreads();
        {
            const int vL2 = leftA ? 0 : done;
            const int vR2 = rightA ? SSPAN : SSPAN - done;
            a = vL2 + ((vR2 - vL2 - 192) * w) / 7;
            #pragma unroll
            for (int j = 0; j < CC; ++j) {
                const float2 u = xbuf[a + lane * CC + j];
                c[j] = u.x; sk[j] = u.y;
            }
        }
        __syncthreads();
    }
}

extern "C" void kernel_launch(void* const* d_in, const int* in_sizes, int n_in,
                              void* d_out, int out_size, void* d_ws, size_t ws_size,
                              hipStream_t stream)
{
    const float* u0 = (const float*)d_in[0];
    FinnPtrs P;
    P.tvec    = (const float*)d_in[1];
    const float* W0      = (const float*)d_in[2];
    const float* b0      = (const float*)d_in[3];
    const float* W1      = (const float*)d_in[4];
    const float* b1      = (const float*)d_in[5];
    const float* W2      = (const float*)d_in[6];
    const float* b2      = (const float*)d_in[7];
    const float* W3      = (const float*)d_in[8];
    const float* b3      = (const float*)d_in[9];
    const float* ret_fac = (const float*)d_in[10];
    P.Dp      = (const float*)d_in[11];
    P.stencil = (const float*)d_in[12];
    P.BCp     = (const float*)d_in[13];
    P.fp      = (const float*)d_in[14];
    P.kdp     = (const float*)d_in[15];
    P.betap   = (const float*)d_in[16];
    P.alphap  = (const float*)d_in[17];
    P.rhosp   = (const float*)d_in[18];
    P.nep     = (const float*)d_in[19];
    P.vep     = (const float*)d_in[20];
    P.dxp     = (const float*)d_in[21];

    float* out     = (float*)d_out;
    float* lut_ret = (float*)d_ws;                       // (LUT_N+1) floats
    float* lut_pw  = (float*)((char*)d_ws + 32768);      // (LUT_N+1) floats
    const int T = in_sizes[1];          // 200

    hipLaunchKernelGGL(finn_lut, dim3((LUT_N + 1 + 255) / 256), dim3(256), 0,
                       stream, W0, b0, W1, b1, W2, b2, W3, b3, ret_fac,
                       P.betap, lut_ret, lut_pw);

    int done = 0;
    while (done < T) {
        const int h = (T - done < MARG) ? (T - done) : MARG;   // 100 + 100
        const float* src = (done == 0) ? u0 : out + (size_t)(done - 1) * NXS * 2;
        float* dst = out + (size_t)done * NXS * 2;
        hipLaunchKernelGGL(finn_sweep, dim3(NB), dim3(BTL), 0, stream,
                           src, dst, lut_ret, lut_pw, P, h);
        done += h;
    }
}

// Round 11
// 62.873 us; speedup vs baseline: 1.4463x; 1.4463x over previous
//
#include <hip/hip_runtime.h>
#include <stdint.h>

#define NXS    65536
#define HID    32
#define BTL    512           // 8 waves per block
#define NB     256           // 1 block/CU
#define OWNB   256           // cells owned per block
#define MARG   200           // halo per side (single launch, T=200)
#define SSPAN  656           // cells spanned per block
#define SLAB   128           // cells per wave slab (2 per lane)
#define EPOCH  24            // steps between refills (even!)
#define LUT_N  4096
#define LUT_INV  512.0f      // entries per unit c, range [-4,4)
#define LUT_BIAS 2048.0f

typedef float    f32x4 __attribute__((ext_vector_type(4)));
typedef uint32_t u32x4 __attribute__((ext_vector_type(4)));

__device__ __forceinline__ float fexp2(float x) { return __builtin_amdgcn_exp2f(x); }
__device__ __forceinline__ float frcp(float x)  { return __builtin_amdgcn_rcpf(x); }
__device__ __forceinline__ float flog2(float x) { return __builtin_amdgcn_logf(x); }

__device__ __forceinline__ float fast_tanh(float x) {
    x = fminf(fmaxf(x, -15.0f), 15.0f);
    float e = fexp2(x * 2.8853900817779268f);
    return (e - 1.0f) * frcp(e + 1.0f);
}
__device__ __forceinline__ float fast_sigmoid(float x) {
    float e = fexp2(x * -1.4426950408889634f);
    return frcp(1.0f + e);
}

struct FinnPtrs {
    const float* tvec;
    const float* Dp;  const float* stencil; const float* BCp; const float* fp;
    const float* kdp; const float* betap;   const float* alphap; const float* rhosp;
    const float* nep; const float* vep;     const float* dxp;
};

// ---- Kernel 1: tabulate ret(c) AND clip(c)^beta on [-4,4], LUT_N+1 entries ----
__global__ __launch_bounds__(256) void finn_lut(
    const float* __restrict__ W0, const float* __restrict__ b0,
    const float* __restrict__ W1, const float* __restrict__ b1,
    const float* __restrict__ W2, const float* __restrict__ b2,
    const float* __restrict__ W3, const float* __restrict__ b3,
    const float* __restrict__ ret_fac, const float* __restrict__ betap,
    float* __restrict__ lut_ret, float* __restrict__ lut_pw)
{
    const int i = blockIdx.x * 256 + threadIdx.x;
    if (i > LUT_N) return;
    const float c = -4.0f + (float)i * (1.0f / LUT_INV);

    float h[HID], a[HID];
    #pragma unroll
    for (int j = 0; j < HID; ++j)
        h[j] = fast_tanh(fmaf(c, W0[j], b0[j]));

    #pragma unroll
    for (int j = 0; j < HID; ++j) a[j] = b1[j];
    #pragma unroll
    for (int k = 0; k < HID; ++k) {
        const float hk = h[k];
        #pragma unroll
        for (int j = 0; j < HID; ++j) a[j] = fmaf(hk, W1[k * HID + j], a[j]);
    }
    #pragma unroll
    for (int j = 0; j < HID; ++j) h[j] = fast_tanh(a[j]);

    #pragma unroll
    for (int j = 0; j < HID; ++j) a[j] = b2[j];
    #pragma unroll
    for (int k = 0; k < HID; ++k) {
        const float hk = h[k];
        #pragma unroll
        for (int j = 0; j < HID; ++j) a[j] = fmaf(hk, W2[k * HID + j], a[j]);
    }
    #pragma unroll
    for (int j = 0; j < HID; ++j) h[j] = fast_tanh(a[j]);

    float pre = b3[0];
    #pragma unroll
    for (int k = 0; k < HID; ++k) pre = fmaf(h[k], W3[k], pre);

    lut_ret[i] = fast_sigmoid(pre) * ret_fac[0];
    lut_pw[i]  = fexp2(betap[0] * flog2(fmaxf(c, 1e-9f)));
}

// ---- Kernel 2: epoch-refill sweep, CC=2 slabs, OOB buffer_store, single launch ----
__global__ __launch_bounds__(BTL, 2) void finn_sweep(
    const float* __restrict__ uin, float* __restrict__ out,
    const float* __restrict__ lr_g, const float* __restrict__ lp_g,
    FinnPtrs P, int T, uint32_t outBytes)
{
    __shared__ f32x4  slut[LUT_N];    // (ret_sl, ret_ic, pw_sl, pw_ic), 64 KB
    __shared__ float2 xbuf[SSPAN];    // refill exchange

    const int tid  = threadIdx.x;
    const int w    = tid >> 6;
    const int lane = tid & 63;

    for (int i = tid; i < LUT_N; i += BTL) {
        const float r0 = lr_g[i], r1 = lr_g[i + 1];
        const float p0 = lp_g[i], p1 = lp_g[i + 1];
        const float rs = r1 - r0, ps = p1 - p0;
        f32x4 e;
        e.x = rs; e.y = fmaf(-(float)i, rs, r0);
        e.z = ps; e.w = fmaf(-(float)i, ps, p0);
        slut[i] = e;
    }

    // wave-uniform scalars
    const float dt   = P.tvec[1] - P.tvec[0];
    const float s0   = P.stencil[0];
    const float s1   = P.stencil[1];
    const float dx   = P.dxp[0];
    const float A    = P.Dp[0] / (dx * dx);
    const float B    = P.vep[0] / dx;
    const float BC   = P.BCp[0];
    const float alp  = P.alphap[0];
    const float akd  = (1.0f - P.fp[0]) * P.kdp[0];
    const float rsne = P.rhosp[0] / P.nep[0];

    const float G    = dt * rsne * alp;
    const float GAKD = G * akd;
    const float S1c  = 1.0f - dt * alp;
    const float S2c  = dt * alp * akd;
    const float K1u  = dt * (2.0f * A * s0 - B);
    const float K2u  = dt * (A * s1 + B);
    const float K3u  = dt * A * s1;

    const int b = blockIdx.x;
    int blockBase = b * OWNB - MARG;
    if (blockBase < 0) blockBase = 0;
    if (blockBase > NXS - SSPAN) blockBase = NXS - SSPAN;
    const bool leftA  = (blockBase == 0);
    const bool rightA = (blockBase == NXS - SSPAN);
    const int ownRelL = b * OWNB - blockBase;
    const int ownRelR = ownRelL + OWNB;

    // SRSRC for OOB-predicated stores (uniform)
    u32x4 srd;
    {
        const uint64_t op = (uint64_t)(uintptr_t)out;
        srd.x = (uint32_t)op;
        srd.y = (uint32_t)(op >> 32);   // stride=0
        srd.z = outBytes;               // num_records: OOB stores dropped
        srd.w = 0x00020000u;
    }

    // epoch-0 slab base (even)
    int a = ((SSPAN - SLAB) * w / 7 + 1) & ~1;

    float c0, sk0, c1, sk1;
    {
        const f32x4* u4 = (const f32x4*)uin;
        const f32x4 u = u4[(blockBase + a + lane * 2) >> 1];
        c0 = u.x; sk0 = u.y; c1 = u.z; sk1 = u.w;
    }

    __syncthreads();   // slut ready

    int done = 0;
    while (done < T) {
        int nst = T - done; if (nst > EPOCH) nst = EPOCH;
        const int si = a + lane * 2;      // even
        const int g0 = blockBase + si;

        // folded K constants (boundary logic absorbed)
        float K0_0 = 0.0f, K1_0 = K1u, K2_0 = K2u;
        const float K3_0 = K3u;
        float K1_1 = K1u, K3_1 = K3u;
        const float K2_1 = K2u;
        if (g0 == 0)           { K0_0 = dt * BC * (2.0f * A * s1 + B);
                                 K1_0 = dt * (3.0f * A * s0 - B); K2_0 = 0.0f; }
        if (g0 + 1 == NXS - 1) { K1_1 = dt * (2.0f * A * s0 - B + A * s1);
                                 K3_1 = 0.0f; }

        // store window (even boundaries, midpoints of adjacent slabs)
        const int vL = leftA ? 0 : done;
        const int vR = rightA ? SSPAN : SSPAN - done;
        const int pd = vR - vL - SLAB;
        const int aPrev = vL + ((pd * (w - 1) / 7 + 1) & ~1);
        const int aNext = vL + ((pd * (w + 1) / 7 + 1) & ~1);
        int bLo = (w == 0) ? 0     : (((aPrev + SLAB + a) >> 1) & ~1);
        int bHi = (w == 7) ? SSPAN : (((a + SLAB + aNext) >> 1) & ~1);
        if (bLo < ownRelL) bLo = ownRelL;
        if (bHi > ownRelR) bHi = ownRelR;
        const bool st = (si >= bLo) && (si < bHi);
        uint32_t voff = st ? (uint32_t)((done * NXS + g0) * 8) : 0x60000000u;

        // prologue comms for first step of epoch
        float clS = __shfl_up(c1, 1);
        float crS = __shfl_down(c0, 1);
        float tt0 = __builtin_amdgcn_fmed3f(fmaf(c0, LUT_INV, LUT_BIAS), 0.0f, 4095.9f);
        f32x4 L0 = slut[(int)tt0];
        float tt1 = __builtin_amdgcn_fmed3f(fmaf(c1, LUT_INV, LUT_BIAS), 0.0f, 4095.9f);
        f32x4 L1 = slut[(int)tt1];

        for (int s = 0; s < nst; ++s) {
            const float ret0 = fmaf(tt0, L0.x, L0.y);
            const float pw0  = fmaf(tt0, L0.z, L0.w);
            const float ret1 = fmaf(tt1, L1.x, L1.y);
            const float pw1  = fmaf(tt1, L1.z, L1.w);
            float t0 = fmaf(K1_0, c0, K0_0);
            t0 = fmaf(K2_0, clS, t0);
            t0 = fmaf(K3_0, c1, t0);
            float t1 = K1_1 * c1;
            t1 = fmaf(K2_1, c0, t1);
            t1 = fmaf(K3_1, crS, t1);
            float v0 = fmaf(ret0, t0, c0); v0 = fmaf(-GAKD, pw0, v0);
            float v1 = fmaf(ret1, t1, c1); v1 = fmaf(-GAKD, pw1, v1);
            const float nc0 = fmaf(G, sk0, v0);
            const float nc1 = fmaf(G, sk1, v1);
            sk0 = fmaf(S1c, sk0, S2c * pw0);
            sk1 = fmaf(S1c, sk1, S2c * pw1);
            c0 = nc0; c1 = nc1;

            // next-step comms issued early (hide DS latency under store+loop)
            clS = __shfl_up(c1, 1);
            crS = __shfl_down(c0, 1);
            tt0 = __builtin_amdgcn_fmed3f(fmaf(c0, LUT_INV, LUT_BIAS), 0.0f, 4095.9f);
            L0 = slut[(int)tt0];
            tt1 = __builtin_amdgcn_fmed3f(fmaf(c1, LUT_INV, LUT_BIAS), 0.0f, 4095.9f);
            L1 = slut[(int)tt1];

            // one 16B store per lane; OOB lanes dropped by hardware
            f32x4 ov; ov.x = c0; ov.y = sk0; ov.z = c1; ov.w = sk1;
            asm volatile("buffer_store_dwordx4 %0, %1, %2, 0 offen"
                         :: "v"(ov), "v"(voff), "s"(srd) : "memory");
            voff += (uint32_t)(NXS * 8);
        }

        done += nst;
        if (done >= T) break;

        // ---- refill: LDS-only barriers (no vmcnt drain; stores stay in flight) ----
        asm volatile("s_waitcnt lgkmcnt(0)" ::: "memory");
        __builtin_amdgcn_s_barrier();
        asm volatile("" ::: "memory");
        {
            const int wLo = (w == 0 && leftA)  ? 0    : EPOCH;
            const int wHi = (w == 7 && rightA) ? SLAB : SLAB - EPOCH;
            const int sr = lane * 2;
            if (sr >= wLo && sr < wHi)         xbuf[a + sr]     = make_float2(c0, sk0);
            if (sr + 1 >= wLo && sr + 1 < wHi) xbuf[a + sr + 1] = make_float2(c1, sk1);
        }
        asm volatile("s_waitcnt lgkmcnt(0)" ::: "memory");
        __builtin_amdgcn_s_barrier();
        asm volatile("" ::: "memory");
        {
            const int vL2 = leftA ? 0 : done;
            const int vR2 = rightA ? SSPAN : SSPAN - done;
            const int pd2 = vR2 - vL2 - SLAB;
            a = vL2 + ((pd2 * w / 7 + 1) & ~1);
            const f32x4 u = *(const f32x4*)&xbuf[a + lane * 2];
            c0 = u.x; sk0 = u.y; c1 = u.z; sk1 = u.w;
        }
        asm volatile("s_waitcnt lgkmcnt(0)" ::: "memory");
        __builtin_amdgcn_s_barrier();
        asm volatile("" ::: "memory");
    }
}

extern "C" void kernel_launch(void* const* d_in, const int* in_sizes, int n_in,
                              void* d_out, int out_size, void* d_ws, size_t ws_size,
                              hipStream_t stream)
{
    const float* u0 = (const float*)d_in[0];
    FinnPtrs P;
    P.tvec    = (const float*)d_in[1];
    const float* W0      = (const float*)d_in[2];
    const float* b0      = (const float*)d_in[3];
    const float* W1      = (const float*)d_in[4];
    const float* b1      = (const float*)d_in[5];
    const float* W2      = (const float*)d_in[6];
    const float* b2      = (const float*)d_in[7];
    const float* W3      = (const float*)d_in[8];
    const float* b3      = (const float*)d_in[9];
    const float* ret_fac = (const float*)d_in[10];
    P.Dp      = (const float*)d_in[11];
    P.stencil = (const float*)d_in[12];
    P.BCp     = (const float*)d_in[13];
    P.fp      = (const float*)d_in[14];
    P.kdp     = (const float*)d_in[15];
    P.betap   = (const float*)d_in[16];
    P.alphap  = (const float*)d_in[17];
    P.rhosp   = (const float*)d_in[18];
    P.nep     = (const float*)d_in[19];
    P.vep     = (const float*)d_in[20];
    P.dxp     = (const float*)d_in[21];

    float* out     = (float*)d_out;
    float* lut_ret = (float*)d_ws;
    float* lut_pw  = (float*)((char*)d_ws + 32768);
    const int T = in_sizes[1];          // 200

    hipLaunchKernelGGL(finn_lut, dim3((LUT_N + 1 + 255) / 256), dim3(256), 0,
                       stream, W0, b0, W1, b1, W2, b2, W3, b3, ret_fac,
                       P.betap, lut_ret, lut_pw);

    hipLaunchKernelGGL(finn_sweep, dim3(NB), dim3(BTL), 0, stream,
                       u0, out, lut_ret, lut_pw, P, T,
                       (uint32_t)out_size * 4u);
}